// Round 5
// baseline (1024.033 us; speedup 1.0000x reference)
//
#include <hip/hip_runtime.h>
#include <stdint.h>

// KNN BC policy: B=1024 x D=512 queries vs N=100000 bank, top-16 L2, mean of acts [1024,32].
// R5: (a) K-loop restructured to minimum-2-phase double-buffer (T3 recipe): BK=32,
// STAGE(next) issued before compute(cur), ONE barrier per kt -> staging latency hidden
// under ds_read+MFMA. (b) Within-round ablation: V0 full (real output), V1 no-selection,
// V2 no-staging (both -> scratch) to attribute the 4x model gap.

#define NQ     1024
#define DIM    512
#define NB     100000
#define NPAD   100352          // 392 * 256
#define NBLK   392             // n-blocks of 256 rows
#define ADIM   32
#define KNB    16
#define NCAND  (NBLK * 8)      // 3136 candidates per query
#define QUARTER (NCAND / 4)    // 784 per wave in topk

typedef __attribute__((ext_vector_type(8)))  _Float16 half8;
typedef __attribute__((ext_vector_type(16))) float f32x16;

__device__ inline int   f2i(float f) { union { float f; int i; } u; u.f = f; return u.i; }
__device__ inline float i2f(int i)   { union { int i; float f; } u; u.i = i; return u.f; }

__device__ inline void gload16(const void* g, void* l) {
  __builtin_amdgcn_global_load_lds(
      (const __attribute__((address_space(1))) unsigned int*)g,
      (__attribute__((address_space(3))) unsigned int*)l, 16, 0, 0);
}

// ---------------- conversion + norms ----------------
__global__ __launch_bounds__(256) void convert_bank_kernel(
    const float* __restrict__ bank, _Float16* __restrict__ bank16,
    float* __restrict__ b2) {
  const int row  = blockIdx.x * 4 + (threadIdx.x >> 6);
  const int lane = threadIdx.x & 63;
  if (row < NB) {
    const float* src = bank + (size_t)row * DIM + lane * 8;
    const float4 a = ((const float4*)src)[0];
    const float4 b = ((const float4*)src)[1];
    float ss = a.x*a.x + a.y*a.y + a.z*a.z + a.w*a.w
             + b.x*b.x + b.y*b.y + b.z*b.z + b.w*b.w;
    #pragma unroll
    for (int o = 32; o; o >>= 1) ss += __shfl_xor(ss, o);
    half8 o8;
    o8[0]=(_Float16)a.x; o8[1]=(_Float16)a.y; o8[2]=(_Float16)a.z; o8[3]=(_Float16)a.w;
    o8[4]=(_Float16)b.x; o8[5]=(_Float16)b.y; o8[6]=(_Float16)b.z; o8[7]=(_Float16)b.w;
    *(half8*)(bank16 + (size_t)row * DIM + lane * 8) = o8;
    if (lane == 0) b2[row] = ss;
  } else {
    half8 z = {0,0,0,0,0,0,0,0};
    *(half8*)(bank16 + (size_t)row * DIM + lane * 8) = z;
    if (lane == 0) b2[row] = 1e30f;   // pad rows never selected
  }
}

__global__ __launch_bounds__(256) void convert_obs_kernel(
    const float* __restrict__ obs, _Float16* __restrict__ o16) {
  const int row  = blockIdx.x * 4 + (threadIdx.x >> 6);
  const int lane = threadIdx.x & 63;
  const float* src = obs + (size_t)row * DIM + lane * 8;
  const float4 a = ((const float4*)src)[0];
  const float4 b = ((const float4*)src)[1];
  half8 o8;
  o8[0]=(_Float16)a.x; o8[1]=(_Float16)a.y; o8[2]=(_Float16)a.z; o8[3]=(_Float16)a.w;
  o8[4]=(_Float16)b.x; o8[5]=(_Float16)b.y; o8[6]=(_Float16)b.z; o8[7]=(_Float16)b.w;
  *(half8*)(o16 + (size_t)row * DIM + lane * 8) = o8;
}

// ---------------- swapped-operand GEMM + in-register top-8 (2-phase dbuf) ----------------
// Block: 256 n-rows x 128 queries. 8 waves = 2 (n-half) x 4 (q-group of 32).
// BK=32, double-buffered LDS; one barrier per K-step; STAGE(next) before compute(cur).
// V0 = full; V1 = no selection (acc reduced to scratch); V2 = no staging (scratch out).
template<int V>
__global__ __launch_bounds__(512) void gemm_select_kernel(
    const _Float16* __restrict__ A16,   // bank fp16 [NPAD][512]
    const _Float16* __restrict__ B16,   // obs  fp16 [1024][512]
    const float* __restrict__ b2,
    float2* __restrict__ cand,
    float* __restrict__ vdiag) {
  __shared__ _Float16 As[2][256 * 32];   // 2 x 16 KB
  __shared__ _Float16 Bs[2][128 * 32];   // 2 x 8 KB
  __shared__ float    b2s[256];
  const int tid = threadIdx.x;
  const int l   = tid & 63;
  const int w   = tid >> 6;
  const int wq  = w & 3;       // query group (32 queries)
  const int wnh = w >> 2;      // n half (128 rows)
  const int nblk = blockIdx.x;
  const int qblk = blockIdx.y;
  const int n0  = nblk * 256;
  const int q0g = qblk * 128;

  if (tid < 256) b2s[tid] = b2[n0 + tid];

  f32x16 acc[4];
  #pragma unroll
  for (int s = 0; s < 4; ++s)
    #pragma unroll
    for (int r = 0; r < 16; ++r) acc[s][r] = 0.f;

  // staging geometry: one gload round = 512 thr x 16B = 8 KB = 128 rows x 64 B.
  // thread -> row = tid>>2, LDS k-slot = tid&3; inverse-swizzled global chunk.
  const int srow = tid >> 2;                       // 0..127
  const int schk = (tid & 3) ^ ((srow >> 1) & 3);  // source chunk for linear dest
  const _Float16* gA = A16 + (size_t)(n0  + srow) * DIM + schk * 8;
  const _Float16* gB = B16 + (size_t)(q0g + srow) * DIM + schk * 8;
  char* abase0 = (char*)(&As[0][0]) + w * 1024;
  char* abase1 = (char*)(&As[1][0]) + w * 1024;
  char* bbase0 = (char*)(&Bs[0][0]) + w * 1024;
  char* bbase1 = (char*)(&Bs[1][0]) + w * 1024;

  auto STAGE = [&](int buf, int t) {
    if constexpr (V != 2) {
      const size_t k0 = (size_t)t * 32;
      char* ab = buf ? abase1 : abase0;
      char* bb = buf ? bbase1 : bbase0;
      gload16(gA + k0,                       ab);
      gload16(gA + k0 + (size_t)128 * DIM,   ab + 8192);
      gload16(gB + k0,                       bb);
    }
  };

  const int rl  = l & 31;
  const int kl  = l >> 5;
  const int swz = (rl >> 1) & 3;    // swizzle term (uniform over ar, br for this lane)

  STAGE(0, 0);
  __syncthreads();                  // buf0 staged (vmcnt drained per wave at barrier)

  for (int t = 0; t < 16; ++t) {
    const int cur = t & 1;
    if (t < 15) STAGE(cur ^ 1, t + 1);       // issue next tile first (T3 recipe)

    const half8* As8 = (const half8*)(&As[cur][0]);
    const half8* Bs8 = (const half8*)(&Bs[cur][0]);
    const int brx = wq * 32 + rl;
    #pragma unroll
    for (int kk = 0; kk < 2; ++kk) {
      const int cl = kk * 2 + kl;
      const half8 bfr = Bs8[brx * 4 + (cl ^ swz)];
      #pragma unroll
      for (int s = 0; s < 4; ++s) {
        const int ar = wnh * 128 + s * 32 + rl;
        const half8 afr = As8[ar * 4 + (cl ^ swz)];
        acc[s] = __builtin_amdgcn_mfma_f32_32x32x16_f16(afr, bfr, acc[s], 0, 0, 0);
      }
    }
    __syncthreads();   // drains my gloads (next buf ready) + all reads of cur done
  }

  if constexpr (V == 1) {
    // keep acc live, measure K-loop only
    float sum = 0.f;
    #pragma unroll
    for (int s = 0; s < 4; ++s)
      #pragma unroll
      for (int r = 0; r < 16; ++r) sum += acc[s][r];
    vdiag[((size_t)qblk * NBLK + nblk) * 512 + tid] = sum;
    return;
  }

  // ---- in-register selection: per-lane smallest-8 over 64 n-scores (one query) ----
  float ts[8]; int ti[8];
  #pragma unroll
  for (int i = 0; i < 8; ++i) { ts[i] = 1e38f; ti[i] = -1; }
  const int rbase = 4 * kl;
  #pragma unroll
  for (int s = 0; s < 4; ++s) {
    #pragma unroll
    for (int r = 0; r < 16; ++r) {
      const int nl = wnh * 128 + s * 32 + (r & 3) + 8 * (r >> 2) + rbase;
      const float sc = fmaf(0.5f, b2s[nl], -acc[s][r]);
      if (sc < ts[7]) {
        float cs = sc; int ci = n0 + nl;
        #pragma unroll
        for (int p = 0; p < 8; ++p) {
          if (cs < ts[p]) {
            float tf = ts[p]; ts[p] = cs; cs = tf;
            int   tt = ti[p]; ti[p] = ci; ci = tt;
          }
        }
      }
    }
  }

  // ---- lane-pair (l ^ 32) head-merge: top-8 of 16, written to mbuf ----
  float2* mbuf = (float2*)(&As[0][0]);   // 16 KB overlay; all LDS reads done
  float2* mrow = mbuf + ((wq * 2 + wnh) * 32 + rl) * 8;
  for (int k = 0; k < 8; ++k) {
    const float ov = __shfl_xor(ts[0], 32);
    const int   oi = __shfl_xor(ti[0], 32);
    const bool mine = (ts[0] < ov) || (ts[0] == ov && kl == 0);
    const float wv = mine ? ts[0] : ov;
    const int   wi = mine ? ti[0] : oi;
    if (mine) {
      #pragma unroll
      for (int p = 0; p < 7; ++p) { ts[p] = ts[p+1]; ti[p] = ti[p+1]; }
      ts[7] = 1e38f; ti[7] = -1;
    }
    if (kl == 0) mrow[k] = make_float2(wv, i2f(wi));
  }
  __syncthreads();

  // ---- cross-n-half merge (sorted 8+8 -> 8) + global store ----
  if (w < 4 && l < 32) {
    const float2* pa = mbuf + ((w * 2 + 0) * 32 + l) * 8;
    const float2* pb = mbuf + ((w * 2 + 1) * 32 + l) * 8;
    float av[8], bv[8]; int ai[8], bi[8];
    #pragma unroll
    for (int j = 0; j < 8; ++j) {
      const float2 ta = pa[j]; av[j] = ta.x; ai[j] = f2i(ta.y);
      const float2 tb = pb[j]; bv[j] = tb.x; bi[j] = f2i(tb.y);
    }
    float2* outp = cand + ((size_t)(q0g + w * 32 + l) * NBLK + nblk) * 8;
    for (int k = 0; k < 8; ++k) {
      const bool ta = (av[0] <= bv[0]);
      outp[k] = make_float2(ta ? av[0] : bv[0], i2f(ta ? ai[0] : bi[0]));
      if (ta) {
        #pragma unroll
        for (int p = 0; p < 7; ++p) { av[p] = av[p+1]; ai[p] = ai[p+1]; }
        av[7] = 1e38f;
      } else {
        #pragma unroll
        for (int p = 0; p < 7; ++p) { bv[p] = bv[p+1]; bi[p] = bi[p+1]; }
        bv[7] = 1e38f;
      }
    }
  }
}

// ---------------- per-query candidate merge + exact rerank ----------------
__global__ __launch_bounds__(256) void topk_kernel(
    const float2* __restrict__ cand, const float* __restrict__ obs,
    const float* __restrict__ bank, const float* __restrict__ acts,
    float* __restrict__ out) {
  __shared__ float2 lc[NCAND];       // 25088 B
  __shared__ float2 wtop[128];
  __shared__ int   selidx[32];
  __shared__ float exd[32];
  __shared__ int   sel2[16];
  const int q    = blockIdx.x;
  const int tid  = threadIdx.x;
  const int lane = tid & 63;
  const int w    = tid >> 6;

  for (int i = tid; i < NCAND; i += 256) lc[i] = cand[(size_t)q * NCAND + i];
  __syncthreads();

  float ts[10]; int ti[10];
  #pragma unroll
  for (int i = 0; i < 10; ++i) { ts[i] = 1e38f; ti[i] = -1; }
  for (int i = w * QUARTER + lane; i < (w + 1) * QUARTER; i += 64) {
    const float2 e = lc[i];
    const float s = e.x;
    if (s < ts[9]) {
      float cs = s; int ci = f2i(e.y);
      #pragma unroll
      for (int pp = 0; pp < 10; ++pp) {
        if (cs < ts[pp]) {
          float tf = ts[pp]; ts[pp] = cs; cs = tf;
          int   tt = ti[pp]; ti[pp] = ci; ci = tt;
        }
      }
    }
  }
  for (int k = 0; k < 32; ++k) {
    float bv = ts[0]; int bi = ti[0]; int bl = lane;
    #pragma unroll
    for (int o = 32; o; o >>= 1) {
      float ov = __shfl_xor(bv, o); int oi = __shfl_xor(bi, o); int ol = __shfl_xor(bl, o);
      if (ov < bv || (ov == bv && ol < bl)) { bv = ov; bi = oi; bl = ol; }
    }
    if (lane == bl) {
      #pragma unroll
      for (int pp = 0; pp < 9; ++pp) { ts[pp] = ts[pp+1]; ti[pp] = ti[pp+1]; }
      ts[9] = 1e38f; ti[9] = -1;
    }
    if (lane == 0) wtop[w * 32 + k] = make_float2(bv, i2f(bi));
  }
  __syncthreads();

  if (w == 0) {
    float2 e0 = wtop[lane], e1 = wtop[64 + lane];
    float s0 = e0.x, s1 = e1.x;
    int   i0 = f2i(e0.y), i1 = f2i(e1.y);
    if (s1 < s0) { float tf = s0; s0 = s1; s1 = tf; int tt = i0; i0 = i1; i1 = tt; }
    for (int k = 0; k < 32; ++k) {
      float bv = s0; int bi = i0; int bl = lane;
      #pragma unroll
      for (int o = 32; o; o >>= 1) {
        float ov = __shfl_xor(bv, o); int oi = __shfl_xor(bi, o); int ol = __shfl_xor(bl, o);
        if (ov < bv || (ov == bv && ol < bl)) { bv = ov; bi = oi; bl = ol; }
      }
      if (lane == bl) { s0 = s1; i0 = i1; s1 = 1e38f; i1 = -1; }
      if (lane == 0) selidx[k] = bi;
    }
  }
  __syncthreads();

  const float* qp = obs + (size_t)q * DIM + lane * 8;
  const float4 qa = ((const float4*)qp)[0];
  const float4 qb = ((const float4*)qp)[1];
  for (int c2 = w; c2 < 32; c2 += 4) {
    const int idx = selidx[c2];
    const float* bp_ = bank + (size_t)idx * DIM + lane * 8;
    const float4 ba = ((const float4*)bp_)[0];
    const float4 bb = ((const float4*)bp_)[1];
    const float d0 = qa.x-ba.x, d1 = qa.y-ba.y, d2 = qa.z-ba.z, d3 = qa.w-ba.w;
    const float d4 = qb.x-bb.x, d5 = qb.y-bb.y, d6 = qb.z-bb.z, d7 = qb.w-bb.w;
    float ss = d0*d0 + d1*d1 + d2*d2 + d3*d3 + d4*d4 + d5*d5 + d6*d6 + d7*d7;
    #pragma unroll
    for (int o = 32; o; o >>= 1) ss += __shfl_xor(ss, o);
    if (lane == 0) exd[c2] = ss;
  }
  __syncthreads();

  if (w == 0) {
    const float v  = (lane < 32) ? exd[lane] : 1e38f;
    const int   id = (lane < 32) ? selidx[lane] : -1;
    float lastv = -1e38f; int lastp = -1;
    for (int k = 0; k < 16; ++k) {
      float bv = 1e38f; int bi = -1; int bp = 64;
      const bool gt = (v > lastv) || (v == lastv && lane > lastp);
      if (gt) { bv = v; bi = id; bp = lane; }
      #pragma unroll
      for (int o = 32; o; o >>= 1) {
        float ov = __shfl_xor(bv, o); int oi = __shfl_xor(bi, o); int op = __shfl_xor(bp, o);
        if (ov < bv || (ov == bv && op < bp)) { bv = ov; bi = oi; bp = op; }
      }
      if (lane == 0) sel2[k] = bi;
      lastv = bv; lastp = bp;
    }
  }
  __syncthreads();

  if (tid < ADIM) {
    float s = 0.f;
    #pragma unroll
    for (int t2 = 0; t2 < KNB; ++t2) s += acts[(size_t)sel2[t2] * ADIM + tid];
    out[(size_t)q * ADIM + tid] = s * (1.0f / KNB);
  }
}

// ---------------- host launch ----------------
extern "C" void kernel_launch(void* const* d_in, const int* in_sizes, int n_in,
                              void* d_out, int out_size, void* d_ws, size_t ws_size,
                              hipStream_t stream) {
  const float* obs  = (const float*)d_in[0];
  const float* bank = (const float*)d_in[1];
  const float* acts = (const float*)d_in[2];
  float* out = (float*)d_out;
  char* ws = (char*)d_ws;

  size_t off = 0;
  auto take = [&](size_t b) { size_t o = off; off += (b + 255) & ~(size_t)255; return o; };
  const size_t off_b16   = take((size_t)NPAD * DIM * 2);          // 102.8 MB
  const size_t off_o16   = take((size_t)NQ * DIM * 2);            // 1 MB
  const size_t off_b2    = take((size_t)NPAD * 4);                // 0.4 MB
  const size_t off_cand  = take((size_t)NQ * NCAND * 8);          // 25.7 MB
  const size_t off_diagv = take((size_t)NBLK * 8 * 512 * 4);      // 6.4 MB (V1 sums)
  const size_t off_diagc = take((size_t)NQ * NCAND * 8);          // 25.7 MB (V2 cand)

  _Float16* bank16 = (_Float16*)(ws + off_b16);
  _Float16* obs16  = (_Float16*)(ws + off_o16);
  float*  b2    = (float*)(ws + off_b2);
  float2* cand  = (float2*)(ws + off_cand);
  float*  diagv = (float*)(ws + off_diagv);
  float2* diagc = (float2*)(ws + off_diagc);

  convert_bank_kernel<<<NPAD / 4, 256, 0, stream>>>(bank, bank16, b2);
  convert_obs_kernel<<<NQ / 4, 256, 0, stream>>>(obs, obs16);

  // V0: real pipeline
  gemm_select_kernel<0><<<dim3(NBLK, NQ / 128), 512, 0, stream>>>(bank16, obs16, b2, cand, diagv);
  // V1: K-loop only (selection ablated)   -> scratch
  gemm_select_kernel<1><<<dim3(NBLK, NQ / 128), 512, 0, stream>>>(bank16, obs16, b2, diagc, diagv);
  // V2: no staging (compute+selection on stale LDS) -> scratch
  gemm_select_kernel<2><<<dim3(NBLK, NQ / 128), 512, 0, stream>>>(bank16, obs16, b2, diagc, diagv);

  topk_kernel<<<NQ, 256, 0, stream>>>(cand, obs, bank, acts, out);
}

// Round 6
// 619.171 us; speedup vs baseline: 1.6539x; 1.6539x over previous
//
#include <hip/hip_runtime.h>
#include <stdint.h>

// KNN BC policy: B=1024 x D=512 queries vs N=100000 bank, top-16 L2, mean of acts [1024,32].
// R6: barrier-free GEMM. No LDS, no staging, no __syncthreads in the K-loop: each wave
// streams A(bank) and B(obs) fragments global->reg (L1/L2-served) with 1-deep manual
// pipelining and accumulates via swapped-operand 32x32x16 fp16 MFMA (query = lane-local).
// R3-R5 showed the stage->barrier structure is latency-bound (every barrier drains
// vmcnt(0) -> serial L2 latency per K-step); this removes every sync point.
// XCD-chunk swizzle (qblk-fast) keeps each 262KB bank slab L2-resident across its 8 q-blocks.

#define NQ     1024
#define DIM    512
#define NB     100000
#define NPAD   100352          // 392 * 256
#define NBLK   392             // n-blocks of 256 rows
#define ADIM   32
#define KNB    16
#define NCAND  (NBLK * 8)      // 3136 candidates per query
#define QUARTER (NCAND / 4)    // 784 per wave in topk

typedef __attribute__((ext_vector_type(8)))  _Float16 half8;
typedef __attribute__((ext_vector_type(16))) float f32x16;

__device__ inline int   f2i(float f) { union { float f; int i; } u; u.f = f; return u.i; }
__device__ inline float i2f(int i)   { union { int i; float f; } u; u.i = i; return u.f; }

// ---------------- conversion + norms ----------------
__global__ __launch_bounds__(256) void convert_bank_kernel(
    const float* __restrict__ bank, _Float16* __restrict__ bank16,
    float* __restrict__ b2) {
  const int row  = blockIdx.x * 4 + (threadIdx.x >> 6);
  const int lane = threadIdx.x & 63;
  if (row < NB) {
    const float* src = bank + (size_t)row * DIM + lane * 8;
    const float4 a = ((const float4*)src)[0];
    const float4 b = ((const float4*)src)[1];
    float ss = a.x*a.x + a.y*a.y + a.z*a.z + a.w*a.w
             + b.x*b.x + b.y*b.y + b.z*b.z + b.w*b.w;
    #pragma unroll
    for (int o = 32; o; o >>= 1) ss += __shfl_xor(ss, o);
    half8 o8;
    o8[0]=(_Float16)a.x; o8[1]=(_Float16)a.y; o8[2]=(_Float16)a.z; o8[3]=(_Float16)a.w;
    o8[4]=(_Float16)b.x; o8[5]=(_Float16)b.y; o8[6]=(_Float16)b.z; o8[7]=(_Float16)b.w;
    *(half8*)(bank16 + (size_t)row * DIM + lane * 8) = o8;
    if (lane == 0) b2[row] = ss;
  } else {
    half8 z = {0,0,0,0,0,0,0,0};
    *(half8*)(bank16 + (size_t)row * DIM + lane * 8) = z;
    if (lane == 0) b2[row] = 1e30f;   // pad rows never selected
  }
}

__global__ __launch_bounds__(256) void convert_obs_kernel(
    const float* __restrict__ obs, _Float16* __restrict__ o16) {
  const int row  = blockIdx.x * 4 + (threadIdx.x >> 6);
  const int lane = threadIdx.x & 63;
  const float* src = obs + (size_t)row * DIM + lane * 8;
  const float4 a = ((const float4*)src)[0];
  const float4 b = ((const float4*)src)[1];
  half8 o8;
  o8[0]=(_Float16)a.x; o8[1]=(_Float16)a.y; o8[2]=(_Float16)a.z; o8[3]=(_Float16)a.w;
  o8[4]=(_Float16)b.x; o8[5]=(_Float16)b.y; o8[6]=(_Float16)b.z; o8[7]=(_Float16)b.w;
  *(half8*)(o16 + (size_t)row * DIM + lane * 8) = o8;
}

// ---------------- barrier-free swapped-operand GEMM + in-register top-8 ----------------
// Block: 256n x 128q, 8 waves = 2 (n-half, 128 rows) x 4 (q-group of 32).
// Each wave: 128n x 32q output = 4 x mfma_32x32x16 acc tiles, fragments straight
// from global (no LDS). D col = lane&31 = query; row = (r&3)+8*(r>>2)+4*(lane>>5).
__global__ __launch_bounds__(512) void gemm_select_kernel(
    const _Float16* __restrict__ A16,   // bank fp16 [NPAD][512]
    const _Float16* __restrict__ B16,   // obs  fp16 [1024][512]
    const float* __restrict__ b2,
    float2* __restrict__ cand) {
  __shared__ float  b2s[256];
  __shared__ float2 mbuf[8 * 32 * 8];   // 16 KB merge buffer

  // bijective XCD-chunk swizzle: 3136 = 8 XCDs x 392; qblk fast within chunk
  const int bid = blockIdx.x;
  const int sb  = (bid & 7) * (NBLK * 8 / 8) + (bid >> 3);
  const int nblk = sb >> 3;
  const int qblk = sb & 7;
  const int n0  = nblk * 256;
  const int q0g = qblk * 128;

  const int tid = threadIdx.x;
  const int l   = tid & 63;
  const int w   = tid >> 6;
  const int wq  = w & 3;       // query group (32 queries)
  const int wnh = w >> 2;      // n half (128 rows)
  const int rl  = l & 31;
  const int kl  = l >> 5;

  if (tid < 256) b2s[tid] = b2[n0 + tid];

  f32x16 acc[4];
  #pragma unroll
  for (int s = 0; s < 4; ++s)
    #pragma unroll
    for (int r = 0; r < 16; ++r) acc[s][r] = 0.f;

  // per-lane fragment base pointers (16B-aligned)
  const _Float16* pA = A16 + (size_t)(n0 + wnh * 128 + rl) * DIM + kl * 8;
  const _Float16* pB = B16 + (size_t)(q0g + wq * 32 + rl) * DIM + kl * 8;

  // 1-deep pipelined K-loop: 32 steps of K=16, zero barriers
  half8 a0 = *(const half8*)(pA);
  half8 a1 = *(const half8*)(pA + 32 * DIM);
  half8 a2 = *(const half8*)(pA + 64 * DIM);
  half8 a3 = *(const half8*)(pA + 96 * DIM);
  half8 bf = *(const half8*)(pB);

  for (int kt = 0; kt < 31; ++kt) {
    const int k1 = (kt + 1) * 16;
    const half8 na0 = *(const half8*)(pA + k1);
    const half8 na1 = *(const half8*)(pA + k1 + 32 * DIM);
    const half8 na2 = *(const half8*)(pA + k1 + 64 * DIM);
    const half8 na3 = *(const half8*)(pA + k1 + 96 * DIM);
    const half8 nbf = *(const half8*)(pB + k1);
    acc[0] = __builtin_amdgcn_mfma_f32_32x32x16_f16(a0, bf, acc[0], 0, 0, 0);
    acc[1] = __builtin_amdgcn_mfma_f32_32x32x16_f16(a1, bf, acc[1], 0, 0, 0);
    acc[2] = __builtin_amdgcn_mfma_f32_32x32x16_f16(a2, bf, acc[2], 0, 0, 0);
    acc[3] = __builtin_amdgcn_mfma_f32_32x32x16_f16(a3, bf, acc[3], 0, 0, 0);
    a0 = na0; a1 = na1; a2 = na2; a3 = na3; bf = nbf;
  }
  acc[0] = __builtin_amdgcn_mfma_f32_32x32x16_f16(a0, bf, acc[0], 0, 0, 0);
  acc[1] = __builtin_amdgcn_mfma_f32_32x32x16_f16(a1, bf, acc[1], 0, 0, 0);
  acc[2] = __builtin_amdgcn_mfma_f32_32x32x16_f16(a2, bf, acc[2], 0, 0, 0);
  acc[3] = __builtin_amdgcn_mfma_f32_32x32x16_f16(a3, bf, acc[3], 0, 0, 0);

  __syncthreads();   // b2s visible (first barrier in the kernel)

  // ---- in-register selection: per-lane smallest-8 over 64 n-scores (one query) ----
  float ts[8]; int ti[8];
  #pragma unroll
  for (int i = 0; i < 8; ++i) { ts[i] = 1e38f; ti[i] = -1; }
  const int rbase = 4 * kl;
  #pragma unroll
  for (int s = 0; s < 4; ++s) {
    #pragma unroll
    for (int r = 0; r < 16; ++r) {
      const int nl = wnh * 128 + s * 32 + (r & 3) + 8 * (r >> 2) + rbase;
      const float sc = fmaf(0.5f, b2s[nl], -acc[s][r]);
      if (sc < ts[7]) {
        float cs = sc; int ci = n0 + nl;
        #pragma unroll
        for (int p = 0; p < 8; ++p) {
          if (cs < ts[p]) {
            float tf = ts[p]; ts[p] = cs; cs = tf;
            int   tt = ti[p]; ti[p] = ci; ci = tt;
          }
        }
      }
    }
  }

  // ---- lane-pair (l ^ 32) head-merge: top-8 of 16 -> mbuf ----
  float2* mrow = mbuf + ((wq * 2 + wnh) * 32 + rl) * 8;
  for (int k = 0; k < 8; ++k) {
    const float ov = __shfl_xor(ts[0], 32);
    const int   oi = __shfl_xor(ti[0], 32);
    const bool mine = (ts[0] < ov) || (ts[0] == ov && kl == 0);
    const float wv = mine ? ts[0] : ov;
    const int   wi = mine ? ti[0] : oi;
    if (mine) {
      #pragma unroll
      for (int p = 0; p < 7; ++p) { ts[p] = ts[p+1]; ti[p] = ti[p+1]; }
      ts[7] = 1e38f; ti[7] = -1;
    }
    if (kl == 0) mrow[k] = make_float2(wv, i2f(wi));
  }
  __syncthreads();

  // ---- cross-n-half merge (sorted 8+8 -> 8) + global store ----
  if (w < 4 && l < 32) {
    const float2* pa = mbuf + ((w * 2 + 0) * 32 + l) * 8;
    const float2* pb = mbuf + ((w * 2 + 1) * 32 + l) * 8;
    float av[8], bv[8]; int ai[8], bi[8];
    #pragma unroll
    for (int j = 0; j < 8; ++j) {
      const float2 ta = pa[j]; av[j] = ta.x; ai[j] = f2i(ta.y);
      const float2 tb = pb[j]; bv[j] = tb.x; bi[j] = f2i(tb.y);
    }
    float2* outp = cand + ((size_t)(q0g + w * 32 + l) * NBLK + nblk) * 8;
    for (int k = 0; k < 8; ++k) {
      const bool ta = (av[0] <= bv[0]);
      outp[k] = make_float2(ta ? av[0] : bv[0], i2f(ta ? ai[0] : bi[0]));
      if (ta) {
        #pragma unroll
        for (int p = 0; p < 7; ++p) { av[p] = av[p+1]; ai[p] = ai[p+1]; }
        av[7] = 1e38f;
      } else {
        #pragma unroll
        for (int p = 0; p < 7; ++p) { bv[p] = bv[p+1]; bi[p] = bi[p+1]; }
        bv[7] = 1e38f;
      }
    }
  }
}

// ---------------- per-query candidate merge + exact rerank ----------------
__global__ __launch_bounds__(256) void topk_kernel(
    const float2* __restrict__ cand, const float* __restrict__ obs,
    const float* __restrict__ bank, const float* __restrict__ acts,
    float* __restrict__ out) {
  __shared__ float2 lc[NCAND];       // 25088 B
  __shared__ float2 wtop[128];
  __shared__ int   selidx[32];
  __shared__ float exd[32];
  __shared__ int   sel2[16];
  const int q    = blockIdx.x;
  const int tid  = threadIdx.x;
  const int lane = tid & 63;
  const int w    = tid >> 6;

  for (int i = tid; i < NCAND; i += 256) lc[i] = cand[(size_t)q * NCAND + i];
  __syncthreads();

  float ts[10]; int ti[10];
  #pragma unroll
  for (int i = 0; i < 10; ++i) { ts[i] = 1e38f; ti[i] = -1; }
  for (int i = w * QUARTER + lane; i < (w + 1) * QUARTER; i += 64) {
    const float2 e = lc[i];
    const float s = e.x;
    if (s < ts[9]) {
      float cs = s; int ci = f2i(e.y);
      #pragma unroll
      for (int pp = 0; pp < 10; ++pp) {
        if (cs < ts[pp]) {
          float tf = ts[pp]; ts[pp] = cs; cs = tf;
          int   tt = ti[pp]; ti[pp] = ci; ci = tt;
        }
      }
    }
  }
  for (int k = 0; k < 32; ++k) {
    float bv = ts[0]; int bi = ti[0]; int bl = lane;
    #pragma unroll
    for (int o = 32; o; o >>= 1) {
      float ov = __shfl_xor(bv, o); int oi = __shfl_xor(bi, o); int ol = __shfl_xor(bl, o);
      if (ov < bv || (ov == bv && ol < bl)) { bv = ov; bi = oi; bl = ol; }
    }
    if (lane == bl) {
      #pragma unroll
      for (int pp = 0; pp < 9; ++pp) { ts[pp] = ts[pp+1]; ti[pp] = ti[pp+1]; }
      ts[9] = 1e38f; ti[9] = -1;
    }
    if (lane == 0) wtop[w * 32 + k] = make_float2(bv, i2f(bi));
  }
  __syncthreads();

  if (w == 0) {
    float2 e0 = wtop[lane], e1 = wtop[64 + lane];
    float s0 = e0.x, s1 = e1.x;
    int   i0 = f2i(e0.y), i1 = f2i(e1.y);
    if (s1 < s0) { float tf = s0; s0 = s1; s1 = tf; int tt = i0; i0 = i1; i1 = tt; }
    for (int k = 0; k < 32; ++k) {
      float bv = s0; int bi = i0; int bl = lane;
      #pragma unroll
      for (int o = 32; o; o >>= 1) {
        float ov = __shfl_xor(bv, o); int oi = __shfl_xor(bi, o); int ol = __shfl_xor(bl, o);
        if (ov < bv || (ov == bv && ol < bl)) { bv = ov; bi = oi; bl = ol; }
      }
      if (lane == bl) { s0 = s1; i0 = i1; s1 = 1e38f; i1 = -1; }
      if (lane == 0) selidx[k] = bi;
    }
  }
  __syncthreads();

  const float* qp = obs + (size_t)q * DIM + lane * 8;
  const float4 qa = ((const float4*)qp)[0];
  const float4 qb = ((const float4*)qp)[1];
  for (int c2 = w; c2 < 32; c2 += 4) {
    const int idx = selidx[c2];
    const float* bp_ = bank + (size_t)idx * DIM + lane * 8;
    const float4 ba = ((const float4*)bp_)[0];
    const float4 bb = ((const float4*)bp_)[1];
    const float d0 = qa.x-ba.x, d1 = qa.y-ba.y, d2 = qa.z-ba.z, d3 = qa.w-ba.w;
    const float d4 = qb.x-bb.x, d5 = qb.y-bb.y, d6 = qb.z-bb.z, d7 = qb.w-bb.w;
    float ss = d0*d0 + d1*d1 + d2*d2 + d3*d3 + d4*d4 + d5*d5 + d6*d6 + d7*d7;
    #pragma unroll
    for (int o = 32; o; o >>= 1) ss += __shfl_xor(ss, o);
    if (lane == 0) exd[c2] = ss;
  }
  __syncthreads();

  if (w == 0) {
    const float v  = (lane < 32) ? exd[lane] : 1e38f;
    const int   id = (lane < 32) ? selidx[lane] : -1;
    float lastv = -1e38f; int lastp = -1;
    for (int k = 0; k < 16; ++k) {
      float bv = 1e38f; int bi = -1; int bp = 64;
      const bool gt = (v > lastv) || (v == lastv && lane > lastp);
      if (gt) { bv = v; bi = id; bp = lane; }
      #pragma unroll
      for (int o = 32; o; o >>= 1) {
        float ov = __shfl_xor(bv, o); int oi = __shfl_xor(bi, o); int op = __shfl_xor(bp, o);
        if (ov < bv || (ov == bv && op < bp)) { bv = ov; bi = oi; bp = op; }
      }
      if (lane == 0) sel2[k] = bi;
      lastv = bv; lastp = bp;
    }
  }
  __syncthreads();

  if (tid < ADIM) {
    float s = 0.f;
    #pragma unroll
    for (int t2 = 0; t2 < KNB; ++t2) s += acts[(size_t)sel2[t2] * ADIM + tid];
    out[(size_t)q * ADIM + tid] = s * (1.0f / KNB);
  }
}

// ---------------- host launch ----------------
extern "C" void kernel_launch(void* const* d_in, const int* in_sizes, int n_in,
                              void* d_out, int out_size, void* d_ws, size_t ws_size,
                              hipStream_t stream) {
  const float* obs  = (const float*)d_in[0];
  const float* bank = (const float*)d_in[1];
  const float* acts = (const float*)d_in[2];
  float* out = (float*)d_out;
  char* ws = (char*)d_ws;

  size_t off = 0;
  auto take = [&](size_t b) { size_t o = off; off += (b + 255) & ~(size_t)255; return o; };
  const size_t off_b16  = take((size_t)NPAD * DIM * 2);          // 102.8 MB
  const size_t off_o16  = take((size_t)NQ * DIM * 2);            // 1 MB
  const size_t off_b2   = take((size_t)NPAD * 4);                // 0.4 MB
  const size_t off_cand = take((size_t)NQ * NCAND * 8);          // 25.7 MB

  _Float16* bank16 = (_Float16*)(ws + off_b16);
  _Float16* obs16  = (_Float16*)(ws + off_o16);
  float*  b2   = (float*)(ws + off_b2);
  float2* cand = (float2*)(ws + off_cand);

  convert_bank_kernel<<<NPAD / 4, 256, 0, stream>>>(bank, bank16, b2);
  convert_obs_kernel<<<NQ / 4, 256, 0, stream>>>(obs, obs16);
  gemm_select_kernel<<<NBLK * 8, 512, 0, stream>>>(bank16, obs16, b2, cand);
  topk_kernel<<<NQ, 256, 0, stream>>>(cand, obs, bank, acts, out);
}

// Round 7
// 421.518 us; speedup vs baseline: 2.4294x; 1.4689x over previous
//
#include <hip/hip_runtime.h>
#include <stdint.h>

// KNN BC policy: B=1024 x D=512 queries vs N=100000 bank, top-16 L2, mean of acts [1024,32].
// R7: counted-vmcnt async GEMM (T3+T4): raw s_barrier (no vmcnt(0) drain), staging loads
// stay in flight across barriers, depth-2 prefetch. Tile 128n x 128q, 4 waves of 64x64
// (64 AGPR), BK=32, dbuf LDS with XOR-swizzle (both-sides w/ global_load_lds).
// Swapped-operand 32x32x16 fp16 MFMA keeps query lane-local -> in-register top-8,
// then per-query merge + exact fp32 rerank of top-32 -> top-16 -> mean.

#define NQ     1024
#define DIM    512
#define NB     100000
#define NPAD   100352          // 784 * 128
#define NBLK   784             // n-blocks of 128 rows
#define ADIM   32
#define KNB    16
#define NCAND  (NBLK * 8)      // 6272 candidates per query
#define QUARTER (NCAND / 4)    // 1568 per wave in topk

typedef __attribute__((ext_vector_type(8)))  _Float16 half8;
typedef __attribute__((ext_vector_type(16))) float f32x16;

__device__ inline int   f2i(float f) { union { float f; int i; } u; u.f = f; return u.i; }
__device__ inline float i2f(int i)   { union { int i; float f; } u; u.i = i; return u.f; }

__device__ inline void gload16(const void* g, void* l) {
  __builtin_amdgcn_global_load_lds(
      (const __attribute__((address_space(1))) unsigned int*)g,
      (__attribute__((address_space(3))) unsigned int*)l, 16, 0, 0);
}

// ---------------- conversion + norms ----------------
__global__ __launch_bounds__(256) void convert_bank_kernel(
    const float* __restrict__ bank, _Float16* __restrict__ bank16,
    float* __restrict__ b2) {
  const int row  = blockIdx.x * 4 + (threadIdx.x >> 6);
  const int lane = threadIdx.x & 63;
  if (row < NB) {
    const float* src = bank + (size_t)row * DIM + lane * 8;
    const float4 a = ((const float4*)src)[0];
    const float4 b = ((const float4*)src)[1];
    float ss = a.x*a.x + a.y*a.y + a.z*a.z + a.w*a.w
             + b.x*b.x + b.y*b.y + b.z*b.z + b.w*b.w;
    #pragma unroll
    for (int o = 32; o; o >>= 1) ss += __shfl_xor(ss, o);
    half8 o8;
    o8[0]=(_Float16)a.x; o8[1]=(_Float16)a.y; o8[2]=(_Float16)a.z; o8[3]=(_Float16)a.w;
    o8[4]=(_Float16)b.x; o8[5]=(_Float16)b.y; o8[6]=(_Float16)b.z; o8[7]=(_Float16)b.w;
    *(half8*)(bank16 + (size_t)row * DIM + lane * 8) = o8;
    if (lane == 0) b2[row] = ss;
  } else {
    half8 z = {0,0,0,0,0,0,0,0};
    *(half8*)(bank16 + (size_t)row * DIM + lane * 8) = z;
    if (lane == 0) b2[row] = 1e30f;   // pad rows never selected
  }
}

__global__ __launch_bounds__(256) void convert_obs_kernel(
    const float* __restrict__ obs, _Float16* __restrict__ o16) {
  const int row  = blockIdx.x * 4 + (threadIdx.x >> 6);
  const int lane = threadIdx.x & 63;
  const float* src = obs + (size_t)row * DIM + lane * 8;
  const float4 a = ((const float4*)src)[0];
  const float4 b = ((const float4*)src)[1];
  half8 o8;
  o8[0]=(_Float16)a.x; o8[1]=(_Float16)a.y; o8[2]=(_Float16)a.z; o8[3]=(_Float16)a.w;
  o8[4]=(_Float16)b.x; o8[5]=(_Float16)b.y; o8[6]=(_Float16)b.z; o8[7]=(_Float16)b.w;
  *(half8*)(o16 + (size_t)row * DIM + lane * 8) = o8;
}

// ---------------- async-pipelined GEMM + in-register top-8 ----------------
// Block 256 thr = 4 waves (2wn x 2wq); wave = 64n x 64q = acc[2][2] 32x32 tiles.
// BK=32 (4 x 16B chunks per row), dbuf; per kt per wave: 4 gload_lds (uniform),
// 8 ds_read_b128, 8 MFMA. vmcnt(4) keeps next tile's loads in flight.
__global__ __launch_bounds__(256, 4) void gemm_select_kernel(
    const _Float16* __restrict__ A16,   // bank fp16 [NPAD][512]
    const _Float16* __restrict__ B16,   // obs  fp16 [1024][512]
    const float* __restrict__ b2,
    float2* __restrict__ cand) {
  __shared__ _Float16 As[2][128 * 32];   // 2 x 8 KB
  __shared__ _Float16 Bs[2][128 * 32];   // 2 x 8 KB
  __shared__ float    b2s[128];

  const int tid = threadIdx.x;
  const int l   = tid & 63;
  const int w   = tid >> 6;
  const int wn  = w >> 1;
  const int wq  = w & 1;
  const int rl  = l & 31;
  const int kl  = l >> 5;

  // bijective XCD-chunk swizzle: 6272 = 8 x 784; q fast within chunk
  const int bid  = blockIdx.x;
  const int sb   = (bid & 7) * (NBLK * 8 / 8) + (bid >> 3);
  const int nblk = sb >> 3;
  const int qblk = sb & 7;
  const int n0   = nblk * 128;
  const int q0   = qblk * 128;

  if (tid < 128) b2s[tid] = b2[n0 + tid];

  f32x16 acc[2][2];
  #pragma unroll
  for (int i = 0; i < 2; ++i)
    #pragma unroll
    for (int j = 0; j < 2; ++j)
      #pragma unroll
      for (int r = 0; r < 16; ++r) acc[i][j][r] = 0.f;

  // staging: wave w stages A-slabs {2w,2w+1}, B-slabs {2w,2w+1}; slab = 16 rows x 64B.
  // dest linear (HW: base + lane*16); source chunk inverse-swizzled: c ^ ((row>>1)&3),
  // row = slab*16 + (l>>2) -> (row>>1)&3 == (l>>3)&3.
  const int sr = l >> 2;
  const int sc = (l & 3) ^ ((l >> 3) & 3);
  const _Float16* gA0 = A16 + (size_t)(n0 + (2 * w) * 16 + sr) * DIM + sc * 8;
  const _Float16* gA1 = gA0 + (size_t)16 * DIM;
  const _Float16* gB0 = B16 + (size_t)(q0 + (2 * w) * 16 + sr) * DIM + sc * 8;
  const _Float16* gB1 = gB0 + (size_t)16 * DIM;

  auto STAGE = [&](int t) {
    const int buf = t & 1;
    const int k0  = t * 32;
    char* ab = (char*)(&As[buf][0]) + (2 * w) * 1024;
    char* bb = (char*)(&Bs[buf][0]) + (2 * w) * 1024;
    gload16(gA0 + k0, ab);
    gload16(gA1 + k0, ab + 1024);
    gload16(gB0 + k0, bb);
    gload16(gB1 + k0, bb + 1024);
  };

  STAGE(0);
  STAGE(1);

  // fragment read rows + loop-invariant swizzle terms
  const int rowa0 = wn * 64 + rl, rowa1 = rowa0 + 32;
  const int rowb0 = wq * 64 + rl, rowb1 = rowb0 + 32;
  const int swa0 = (rowa0 >> 1) & 3, swa1 = (rowa1 >> 1) & 3;
  const int swb0 = (rowb0 >> 1) & 3, swb1 = (rowb1 >> 1) & 3;

  #pragma unroll 1
  for (int t = 0; t < 15; ++t) {
    asm volatile("s_waitcnt vmcnt(4)" ::: "memory");   // t's loads done; t+1's in flight
    __builtin_amdgcn_s_barrier();
    __builtin_amdgcn_sched_barrier(0);
    const half8* A8 = (const half8*)(&As[t & 1][0]);
    const half8* B8 = (const half8*)(&Bs[t & 1][0]);
    #pragma unroll
    for (int ks = 0; ks < 2; ++ks) {
      const int c = ks * 2 + kl;
      const half8 a0 = A8[rowa0 * 4 + (c ^ swa0)];
      const half8 a1 = A8[rowa1 * 4 + (c ^ swa1)];
      const half8 b0 = B8[rowb0 * 4 + (c ^ swb0)];
      const half8 b1 = B8[rowb1 * 4 + (c ^ swb1)];
      acc[0][0] = __builtin_amdgcn_mfma_f32_32x32x16_f16(a0, b0, acc[0][0], 0, 0, 0);
      acc[0][1] = __builtin_amdgcn_mfma_f32_32x32x16_f16(a0, b1, acc[0][1], 0, 0, 0);
      acc[1][0] = __builtin_amdgcn_mfma_f32_32x32x16_f16(a1, b0, acc[1][0], 0, 0, 0);
      acc[1][1] = __builtin_amdgcn_mfma_f32_32x32x16_f16(a1, b1, acc[1][1], 0, 0, 0);
    }
    __builtin_amdgcn_sched_barrier(0);
    __builtin_amdgcn_s_barrier();   // all reads of buf done -> safe to overwrite
    if (t < 14) STAGE(t + 2);
  }
  // peeled last iter: drain everything
  {
    asm volatile("s_waitcnt vmcnt(0)" ::: "memory");
    __builtin_amdgcn_s_barrier();
    __builtin_amdgcn_sched_barrier(0);
    const half8* A8 = (const half8*)(&As[1][0]);
    const half8* B8 = (const half8*)(&Bs[1][0]);
    #pragma unroll
    for (int ks = 0; ks < 2; ++ks) {
      const int c = ks * 2 + kl;
      const half8 a0 = A8[rowa0 * 4 + (c ^ swa0)];
      const half8 a1 = A8[rowa1 * 4 + (c ^ swa1)];
      const half8 b0 = B8[rowb0 * 4 + (c ^ swb0)];
      const half8 b1 = B8[rowb1 * 4 + (c ^ swb1)];
      acc[0][0] = __builtin_amdgcn_mfma_f32_32x32x16_f16(a0, b0, acc[0][0], 0, 0, 0);
      acc[0][1] = __builtin_amdgcn_mfma_f32_32x32x16_f16(a0, b1, acc[0][1], 0, 0, 0);
      acc[1][0] = __builtin_amdgcn_mfma_f32_32x32x16_f16(a1, b0, acc[1][0], 0, 0, 0);
      acc[1][1] = __builtin_amdgcn_mfma_f32_32x32x16_f16(a1, b1, acc[1][1], 0, 0, 0);
    }
    __builtin_amdgcn_sched_barrier(0);
    __builtin_amdgcn_s_barrier();
  }

  // ---- selection: per qs (two 32q groups), per-lane top-8 over 32 n-scores ----
  float2* mbuf = (float2*)(&As[0][0]);   // 16 KB overlay: [wn][wq][qs][32][8]
  #pragma unroll
  for (int qs = 0; qs < 2; ++qs) {
    float ts[8]; int ti[8];
    #pragma unroll
    for (int i = 0; i < 8; ++i) { ts[i] = 1e38f; ti[i] = -1; }
    #pragma unroll
    for (int ns = 0; ns < 2; ++ns) {
      #pragma unroll
      for (int r = 0; r < 16; ++r) {
        const int nl = wn * 64 + ns * 32 + (r & 3) + 8 * (r >> 2) + 4 * kl;
        const float sc2 = fmaf(0.5f, b2s[nl], -acc[ns][qs][r]);
        if (sc2 < ts[7]) {
          float cs = sc2; int ci = n0 + nl;
          #pragma unroll
          for (int p = 0; p < 8; ++p) {
            if (cs < ts[p]) {
              float tf = ts[p]; ts[p] = cs; cs = tf;
              int   tt = ti[p]; ti[p] = ci; ci = tt;
            }
          }
        }
      }
    }
    // lane-pair (l^32) head-merge -> top-8 of this wave's 64 n for query (rl)
    float2* mrow = mbuf + ((((wn * 2 + wq) * 2 + qs) * 32) + rl) * 8;
    for (int k = 0; k < 8; ++k) {
      const float ov = __shfl_xor(ts[0], 32);
      const int   oi = __shfl_xor(ti[0], 32);
      const bool mine = (ts[0] < ov) || (ts[0] == ov && kl == 0);
      const float wv = mine ? ts[0] : ov;
      const int   wi = mine ? ti[0] : oi;
      if (mine) {
        #pragma unroll
        for (int p = 0; p < 7; ++p) { ts[p] = ts[p+1]; ti[p] = ti[p+1]; }
        ts[7] = 1e38f; ti[7] = -1;
      }
      if (kl == 0) mrow[k] = make_float2(wv, i2f(wi));
    }
  }
  __syncthreads();

  // ---- cross-wn merge (sorted 8+8 -> 8) + global store; 128 q-slots ----
  if (tid < 128) {
    const int wq_f = tid >> 6;
    const int qs_f = (tid >> 5) & 1;
    const int rl_f = tid & 31;
    const float2* pa = mbuf + ((((0 * 2 + wq_f) * 2 + qs_f) * 32) + rl_f) * 8;
    const float2* pb = mbuf + ((((1 * 2 + wq_f) * 2 + qs_f) * 32) + rl_f) * 8;
    float av[8], bv[8]; int ai[8], bi[8];
    #pragma unroll
    for (int j = 0; j < 8; ++j) {
      const float2 ta = pa[j]; av[j] = ta.x; ai[j] = f2i(ta.y);
      const float2 tb = pb[j]; bv[j] = tb.x; bi[j] = f2i(tb.y);
    }
    const int q = q0 + wq_f * 64 + qs_f * 32 + rl_f;
    float2* outp = cand + ((size_t)q * NBLK + nblk) * 8;
    for (int k = 0; k < 8; ++k) {
      const bool ta = (av[0] <= bv[0]);
      outp[k] = make_float2(ta ? av[0] : bv[0], i2f(ta ? ai[0] : bi[0]));
      if (ta) {
        #pragma unroll
        for (int p = 0; p < 7; ++p) { av[p] = av[p+1]; ai[p] = ai[p+1]; }
        av[7] = 1e38f;
      } else {
        #pragma unroll
        for (int p = 0; p < 7; ++p) { bv[p] = bv[p+1]; bi[p] = bi[p+1]; }
        bv[7] = 1e38f;
      }
    }
  }
}

// ---------------- per-query candidate merge + exact rerank ----------------
__global__ __launch_bounds__(256) void topk_kernel(
    const float2* __restrict__ cand, const float* __restrict__ obs,
    const float* __restrict__ bank, const float* __restrict__ acts,
    float* __restrict__ out) {
  __shared__ float2 lc[NCAND];       // 50176 B
  __shared__ float2 wtop[128];
  __shared__ int   selidx[32];
  __shared__ float exd[32];
  __shared__ int   sel2[16];
  const int q    = blockIdx.x;
  const int tid  = threadIdx.x;
  const int lane = tid & 63;
  const int w    = tid >> 6;

  for (int i = tid; i < NCAND; i += 256) lc[i] = cand[(size_t)q * NCAND + i];
  __syncthreads();

  float ts[10]; int ti[10];
  #pragma unroll
  for (int i = 0; i < 10; ++i) { ts[i] = 1e38f; ti[i] = -1; }
  for (int i = w * QUARTER + lane; i < (w + 1) * QUARTER; i += 64) {
    const float2 e = lc[i];
    const float s = e.x;
    if (s < ts[9]) {
      float cs = s; int ci = f2i(e.y);
      #pragma unroll
      for (int pp = 0; pp < 10; ++pp) {
        if (cs < ts[pp]) {
          float tf = ts[pp]; ts[pp] = cs; cs = tf;
          int   tt = ti[pp]; ti[pp] = ci; ci = tt;
        }
      }
    }
  }
  for (int k = 0; k < 32; ++k) {
    float bv = ts[0]; int bi = ti[0]; int bl = lane;
    #pragma unroll
    for (int o = 32; o; o >>= 1) {
      float ov = __shfl_xor(bv, o); int oi = __shfl_xor(bi, o); int ol = __shfl_xor(bl, o);
      if (ov < bv || (ov == bv && ol < bl)) { bv = ov; bi = oi; bl = ol; }
    }
    if (lane == bl) {
      #pragma unroll
      for (int pp = 0; pp < 9; ++pp) { ts[pp] = ts[pp+1]; ti[pp] = ti[pp+1]; }
      ts[9] = 1e38f; ti[9] = -1;
    }
    if (lane == 0) wtop[w * 32 + k] = make_float2(bv, i2f(bi));
  }
  __syncthreads();

  if (w == 0) {
    float2 e0 = wtop[lane], e1 = wtop[64 + lane];
    float s0 = e0.x, s1 = e1.x;
    int   i0 = f2i(e0.y), i1 = f2i(e1.y);
    if (s1 < s0) { float tf = s0; s0 = s1; s1 = tf; int tt = i0; i0 = i1; i1 = tt; }
    for (int k = 0; k < 32; ++k) {
      float bv = s0; int bi = i0; int bl = lane;
      #pragma unroll
      for (int o = 32; o; o >>= 1) {
        float ov = __shfl_xor(bv, o); int oi = __shfl_xor(bi, o); int ol = __shfl_xor(bl, o);
        if (ov < bv || (ov == bv && ol < bl)) { bv = ov; bi = oi; bl = ol; }
      }
      if (lane == bl) { s0 = s1; i0 = i1; s1 = 1e38f; i1 = -1; }
      if (lane == 0) selidx[k] = bi;
    }
  }
  __syncthreads();

  const float* qp = obs + (size_t)q * DIM + lane * 8;
  const float4 qa = ((const float4*)qp)[0];
  const float4 qb = ((const float4*)qp)[1];
  for (int c2 = w; c2 < 32; c2 += 4) {
    const int idx = selidx[c2];
    const float* bp_ = bank + (size_t)idx * DIM + lane * 8;
    const float4 ba = ((const float4*)bp_)[0];
    const float4 bb = ((const float4*)bp_)[1];
    const float d0 = qa.x-ba.x, d1 = qa.y-ba.y, d2 = qa.z-ba.z, d3 = qa.w-ba.w;
    const float d4 = qb.x-bb.x, d5 = qb.y-bb.y, d6 = qb.z-bb.z, d7 = qb.w-bb.w;
    float ss = d0*d0 + d1*d1 + d2*d2 + d3*d3 + d4*d4 + d5*d5 + d6*d6 + d7*d7;
    #pragma unroll
    for (int o = 32; o; o >>= 1) ss += __shfl_xor(ss, o);
    if (lane == 0) exd[c2] = ss;
  }
  __syncthreads();

  if (w == 0) {
    const float v  = (lane < 32) ? exd[lane] : 1e38f;
    const int   id = (lane < 32) ? selidx[lane] : -1;
    float lastv = -1e38f; int lastp = -1;
    for (int k = 0; k < 16; ++k) {
      float bv = 1e38f; int bi = -1; int bp = 64;
      const bool gt = (v > lastv) || (v == lastv && lane > lastp);
      if (gt) { bv = v; bi = id; bp = lane; }
      #pragma unroll
      for (int o = 32; o; o >>= 1) {
        float ov = __shfl_xor(bv, o); int oi = __shfl_xor(bi, o); int op = __shfl_xor(bp, o);
        if (ov < bv || (ov == bv && op < bp)) { bv = ov; bi = oi; bp = op; }
      }
      if (lane == 0) sel2[k] = bi;
      lastv = bv; lastp = bp;
    }
  }
  __syncthreads();

  if (tid < ADIM) {
    float s = 0.f;
    #pragma unroll
    for (int t2 = 0; t2 < KNB; ++t2) s += acts[(size_t)sel2[t2] * ADIM + tid];
    out[(size_t)q * ADIM + tid] = s * (1.0f / KNB);
  }
}

// ---------------- host launch ----------------
extern "C" void kernel_launch(void* const* d_in, const int* in_sizes, int n_in,
                              void* d_out, int out_size, void* d_ws, size_t ws_size,
                              hipStream_t stream) {
  const float* obs  = (const float*)d_in[0];
  const float* bank = (const float*)d_in[1];
  const float* acts = (const float*)d_in[2];
  float* out = (float*)d_out;
  char* ws = (char*)d_ws;

  size_t off = 0;
  auto take = [&](size_t b) { size_t o = off; off += (b + 255) & ~(size_t)255; return o; };
  const size_t off_b16  = take((size_t)NPAD * DIM * 2);          // 102.8 MB
  const size_t off_o16  = take((size_t)NQ * DIM * 2);            // 1 MB
  const size_t off_b2   = take((size_t)NPAD * 4);                // 0.4 MB
  const size_t off_cand = take((size_t)NQ * NCAND * 8);          // 51.4 MB

  _Float16* bank16 = (_Float16*)(ws + off_b16);
  _Float16* obs16  = (_Float16*)(ws + off_o16);
  float*  b2   = (float*)(ws + off_b2);
  float2* cand = (float2*)(ws + off_cand);

  convert_bank_kernel<<<NPAD / 4, 256, 0, stream>>>(bank, bank16, b2);
  convert_obs_kernel<<<NQ / 4, 256, 0, stream>>>(obs, obs16);
  gemm_select_kernel<<<NBLK * 8, 256, 0, stream>>>(bank16, obs16, b2, cand);
  topk_kernel<<<NQ, 256, 0, stream>>>(cand, obs, bank, acts, out);
}